// Round 1
// baseline (267.554 us; speedup 1.0000x reference)
//
#include <hip/hip_runtime.h>
#include <math.h>

#define KE 14.399645351950548f

__device__ __forceinline__ float softplusf(float x) {
    // log1p(exp(x)); raw params here are ~[-3.6, 3.2] so no overflow concerns,
    // but keep the guard anyway.
    return (x > 20.0f) ? x : log1pf(__expf(x));
}

struct ZblParams { float a1, a2, a3, a4, c1, c2, c3, c4, p, d; };

__global__ __launch_bounds__(256) void ZBLRepulsion_kernel(
    const float* __restrict__ z,          // atomic_numbers [N]
    const float* __restrict__ cut,        // cutoffs  [E]
    const int*   __restrict__ snd,        // senders  [E]
    const int*   __restrict__ rcv,        // receivers[E]
    const float* __restrict__ len,        // lengths  [E]
    const float* __restrict__ a1r, const float* __restrict__ a2r,
    const float* __restrict__ a3r, const float* __restrict__ a4r,
    const float* __restrict__ c1r, const float* __restrict__ c2r,
    const float* __restrict__ c3r, const float* __restrict__ c4r,
    const float* __restrict__ pr,  const float* __restrict__ dr,
    float* __restrict__ out,              // [N], pre-zeroed
    int n4, int E)
{
    // Per-block scalar-param prep: 10 softplus once per block, not per thread.
    __shared__ ZblParams P;
    if (threadIdx.x == 0) {
        float a1 = softplusf(a1r[0]), a2 = softplusf(a2r[0]);
        float a3 = softplusf(a3r[0]), a4 = softplusf(a4r[0]);
        float c1 = softplusf(c1r[0]), c2 = softplusf(c2r[0]);
        float c3 = softplusf(c3r[0]), c4 = softplusf(c4r[0]);
        float inv = 1.0f / (c1 + c2 + c3 + c4);
        P.a1 = a1; P.a2 = a2; P.a3 = a3; P.a4 = a4;
        P.c1 = c1 * inv; P.c2 = c2 * inv; P.c3 = c3 * inv; P.c4 = c4 * inv;
        P.p  = softplusf(pr[0]);
        P.d  = softplusf(dr[0]);
    }
    __syncthreads();

    const float pa1 = P.a1, pa2 = P.a2, pa3 = P.a3, pa4 = P.a4;
    const float pc1 = P.c1, pc2 = P.c2, pc3 = P.c3, pc4 = P.c4;
    const float pp = P.p, pd = P.d;

    int i = blockIdx.x * blockDim.x + threadIdx.x;
    if (i >= n4) return;

    float cs[4], Ls[4];
    int ss[4], rr[4];
    int base = i * 4;
    int cnt;
    if (base + 4 <= E) {
        // 16 B/lane vector loads on the four edge streams.
        float4 c4v = ((const float4*)cut)[i];
        float4 l4v = ((const float4*)len)[i];
        int4   s4v = ((const int4*)snd)[i];
        int4   r4v = ((const int4*)rcv)[i];
        cs[0]=c4v.x; cs[1]=c4v.y; cs[2]=c4v.z; cs[3]=c4v.w;
        Ls[0]=l4v.x; Ls[1]=l4v.y; Ls[2]=l4v.z; Ls[3]=l4v.w;
        ss[0]=s4v.x; ss[1]=s4v.y; ss[2]=s4v.z; ss[3]=s4v.w;
        rr[0]=r4v.x; rr[1]=r4v.y; rr[2]=r4v.z; rr[3]=r4v.w;
        cnt = 4;
    } else {
        cnt = E - base;
        for (int k = 0; k < cnt; ++k) {
            cs[k] = cut[base + k];
            Ls[k] = len[base + k];
            ss[k] = snd[base + k];
            rr[k] = rcv[base + k];
        }
    }

    #pragma unroll
    for (int k = 0; k < 4; ++k) {
        if (k >= cnt) break;
        float l = Ls[k];
        float c = l * (1.0f / 1.5f);          // _switch(L, 0, 1.5)
        float om = 1.0f - c;
        // If om <= 0: s1 == 0 exactly (jnp.where branch) -> w == 0 -> edge
        // contributes exactly 0. ~60% of edges (L>=1.5) skip everything.
        if (om > 0.0f) {
            float zi = z[rr[k]];
            float zj = z[ss[k]];
            float s1 = __expf(-1.0f / fmaxf(om, 1e-12f));
            float s0 = (c > 0.0f) ? __expf(-1.0f / fmaxf(c, 1e-12f)) : 0.0f;
            float w  = s1 / (s1 + s0 + 1e-12f);
            float x  = KE * cs[k] * zi * zj / fmaxf(l, 1e-6f);
            float rzd = l * (__powf(zi, pp) + __powf(zj, pp)) * pd;
            float y = pc1 * __expf(-pa1 * rzd) + pc2 * __expf(-pa2 * rzd)
                    + pc3 * __expf(-pa3 * rzd) + pc4 * __expf(-pa4 * rzd);
            float e_rep = 0.5f * w * x * y;
            atomicAdd(&out[rr[k]], e_rep);
        }
    }
}

extern "C" void kernel_launch(void* const* d_in, const int* in_sizes, int n_in,
                              void* d_out, int out_size, void* d_ws, size_t ws_size,
                              hipStream_t stream) {
    const float* z   = (const float*)d_in[0];   // atomic_numbers [N]
    const float* cut = (const float*)d_in[1];   // cutoffs [E]
    const int*   snd = (const int*)d_in[2];     // senders [E]
    const int*   rcv = (const int*)d_in[3];     // receivers [E]
    const float* len = (const float*)d_in[4];   // lengths [E]
    // d_in[5] = num_nodes (int scalar); out_size == N already.
    const float* a1r = (const float*)d_in[6];
    const float* a2r = (const float*)d_in[7];
    const float* a3r = (const float*)d_in[8];
    const float* a4r = (const float*)d_in[9];
    const float* c1r = (const float*)d_in[10];
    const float* c2r = (const float*)d_in[11];
    const float* c3r = (const float*)d_in[12];
    const float* c4r = (const float*)d_in[13];
    const float* pr  = (const float*)d_in[14];
    const float* dr  = (const float*)d_in[15];

    float* out = (float*)d_out;
    int E = in_sizes[2];      // senders count
    int N = out_size;

    // Output is poisoned each call; zero it (memset node is graph-capturable).
    hipMemsetAsync(d_out, 0, (size_t)N * sizeof(float), stream);

    int n4 = (E + 3) / 4;
    int threads = 256;
    int blocks = (n4 + threads - 1) / threads;
    hipLaunchKernelGGL(ZBLRepulsion_kernel, dim3(blocks), dim3(threads), 0, stream,
                       z, cut, snd, rcv, len,
                       a1r, a2r, a3r, a4r, c1r, c2r, c3r, c4r, pr, dr,
                       out, n4, E);
}